// Round 6
// baseline (223.927 us; speedup 1.0000x reference)
//
#include <hip/hip_runtime.h>
#include <math.h>

#define NPTS 32768
#define DD 8
#define OO 20      // ORDER+1
#define PP 20
#define NCHAIN 7   // c=0: mean chain; c=1..6: variance moment k=c

typedef _Float16 half8 __attribute__((ext_vector_type(8)));
typedef __fp16 fp16x2 __attribute__((ext_vector_type(2)));
typedef float floatx16 __attribute__((ext_vector_type(16)));

// sigma: row permutation baked into A so that C-layout output == next B layout
// (swap rows 4..7 <-> 8..11; identity elsewhere)
__device__ __forceinline__ int sigma_row(int m) {
    return (m >= 4 && m < 12) ? (m ^ 12) : m;
}

// ---------------------------------------------------------------------------
// Prep:
//   W0[c][p][q]  fp32 = c==0 ? exp(meanw0) : exp(2*meanw0 + c*varw0)
//   WA[c][i][p][m][k] f16 (32x32, zero-padded) = W[sigma(m)][k] where
//       W[q'][o] = c==0 ? exp(meanw[i][p][o][q']) : exp(2*m + c*v)
// binom stays in the fp32 gate (up to 92378 > f16 max; basis in [0,1]).
// ---------------------------------------------------------------------------
__global__ void prep_kernel(const float* __restrict__ meanw0,
                            const float* __restrict__ meanw,
                            const float* __restrict__ varw0,
                            const float* __restrict__ varw,
                            float* __restrict__ W0,
                            _Float16* __restrict__ WA) {
    int e = blockIdx.x * 256 + threadIdx.x;
    const int n0 = NCHAIN * PP * OO;                 // 2800
    const int nW = NCHAIN * (DD - 1) * PP * 32 * 32; // 1,003,520
    if (e < n0) {
        int q = e % OO;
        int rem = e / OO;
        int p = rem % PP;
        int c = rem / PP;
        float m = meanw0[p * OO + q];
        W0[e] = (c == 0) ? __expf(m) : __expf(2.f * m + (float)c * varw0[p * OO + q]);
    } else if (e < n0 + nW) {
        int idx = e - n0;
        int k = idx & 31; idx >>= 5;
        int m = idx & 31; idx >>= 5;
        int p = idx % PP; idx /= PP;
        int i = idx % (DD - 1);
        int c = idx / (DD - 1);
        int q = sigma_row(m);
        float v = 0.f;
        if (q < OO && k < OO) {
            int mi = ((i * PP + p) * OO + k) * OO + q;   // meanw[i][p][o=k][q']
            float mm = meanw[mi];
            v = (c == 0) ? __expf(mm) : __expf(2.f * mm + (float)c * varw[mi]);
        }
        WA[e - n0] = (_Float16)v;
    }
}

// basis b_q = binom[q] t^q (1-t)^(19-q), fp32
__device__ __forceinline__ void basis20(float tv, float* g) {
    constexpr float binom[OO] = {
        1.f, 19.f, 171.f, 969.f, 3876.f, 11628.f, 27132.f, 50388.f, 75582.f,
        92378.f, 92378.f, 75582.f, 50388.f, 27132.f, 11628.f, 3876.f, 969.f,
        171.f, 19.f, 1.f};
    float a = tv, b = 1.f - tv, v = 1.f;
#pragma unroll
    for (int q = 0; q < OO; ++q) { g[q] = v; v *= a; }
    v = 1.f;
#pragma unroll
    for (int q = OO - 1; q >= 0; --q) { g[q] = g[q] * v * binom[q]; v *= b; }
}

__device__ __forceinline__ unsigned pack_pk(float x, float y) {
    union { fp16x2 h; unsigned u; } cv;
    cv.h = __builtin_amdgcn_cvt_pkrtz(x, y);
    return cv.u;
}

// ---------------------------------------------------------------------------
// One wave = one p x 32 points x all 7 chains. State st[c][0..5] is the f16
// B-layout activation (B[k][n]=f[k], n=lane&31, k=8*hi+j / 16+8*hi+j).
// Thanks to the sigma row permutation of A, the MFMA C output at each lane
// packs DIRECTLY into that lane's next-step B dwords:
//   B0.u[e] = pk[e];  B1 = {st[4], st[5], 0, 0}
// (hi-half upper packs are exact zeros: A' rows 20..23 are zero.)
// Gate in C-space: reg r multiplies g[r+8*hi] (r<8), g[r+8]/0 (r>=8).
// No DS ops in the loop; per chain-step: 12 mul + 6 pkrtz + 2 MFMA.
// ---------------------------------------------------------------------------
__global__ __launch_bounds__(256, 3) void chain_kernel(
    const float* __restrict__ X, const int* __restrict__ perm,
    const float* __restrict__ W0, const _Float16* __restrict__ WA,
    float* __restrict__ out) {
    const int lane = threadIdx.x & 63;
    const int wv = threadIdx.x >> 6;
    const int nl = lane & 31;
    const bool hi = (lane >> 5) != 0;
    const int n0 = (blockIdx.x * 4 + wv) * 32;
    const int p = blockIdx.y;

    // permuted X entries for this wave's 32 points (perm is wave-uniform)
    float t[DD];
#pragma unroll
    for (int i = 0; i < DD; ++i)
        t[i] = X[(size_t)(n0 + nl) * DD + perm[p * DD + i]];

    unsigned st[NCHAIN][6];

    // ---- init directly in B layout: f0[k] = W0[c][p][k] * gate0[k] ----
    {
        float g[OO];
        basis20(t[0], g);
        float gc[12], gc2[12];
#pragma unroll
        for (int r = 0; r < 8; ++r) gc[r] = hi ? g[r + 8] : g[r];
#pragma unroll
        for (int r = 8; r < 12; ++r) gc[r] = hi ? 0.f : g[r + 8];
#pragma unroll
        for (int r = 0; r < 12; ++r) gc2[r] = gc[r] * gc[r];
#pragma unroll
        for (int c = 0; c < NCHAIN; ++c) {
            const float* w0r = W0 + (c * PP + p) * OO;
            float val[12];
#pragma unroll
            for (int r = 0; r < 8; ++r) {
                float ws = hi ? w0r[r + 8] : w0r[r];
                val[r] = ws * (c == 0 ? gc[r] : gc2[r]);
            }
#pragma unroll
            for (int r = 8; r < 12; ++r) {
                float ws = hi ? 0.f : w0r[r + 8];
                val[r] = ws * (c == 0 ? gc[r] : gc2[r]);
            }
#pragma unroll
            for (int e = 0; e < 6; ++e)
                st[c][e] = pack_pk(val[2 * e], val[2 * e + 1]);
        }
    }

    // per-lane A-operand offset (A row m = nl, k = hi*8 + j; +16 for MFMA1)
    const int aoff = nl * 32 + (hi ? 8 : 0);
    const float coef[NCHAIN] = {0.f, 1.f, 0.5f, 1.f / 6.f, 1.f / 24.f,
                                1.f / 120.f, 1.f / 720.f};
    float sm = 0.f, sv = 0.f;

#pragma unroll
    for (int i = 1; i < DD; ++i) {
        float g[OO];
        basis20(t[i], g);
        float gc[12], gc2[12];
#pragma unroll
        for (int r = 0; r < 8; ++r) gc[r] = hi ? g[r + 8] : g[r];
#pragma unroll
        for (int r = 8; r < 12; ++r) gc[r] = hi ? 0.f : g[r + 8];
#pragma unroll
        for (int r = 0; r < 12; ++r) gc2[r] = gc[r] * gc[r];

#pragma unroll
        for (int c = 0; c < NCHAIN; ++c) {
            union { unsigned u[4]; half8 h; } B0, B1;
            B0.u[0] = st[c][0]; B0.u[1] = st[c][1];
            B0.u[2] = st[c][2]; B0.u[3] = st[c][3];
            B1.u[0] = st[c][4]; B1.u[1] = st[c][5];
            B1.u[2] = 0u;       B1.u[3] = 0u;

            const _Float16* wa =
                WA + (size_t)(((c * (DD - 1)) + (i - 1)) * PP + p) * 1024 + aoff;
            half8 A0 = *(const half8*)(wa);
            half8 A1 = *(const half8*)(wa + 16);

            floatx16 acc = {};
            acc = __builtin_amdgcn_mfma_f32_32x32x16_f16(A0, B0.h, acc, 0, 0, 0);
            acc = __builtin_amdgcn_mfma_f32_32x32x16_f16(A1, B1.h, acc, 0, 0, 0);

            if (i < DD - 1) {
                float val[12];
#pragma unroll
                for (int r = 0; r < 12; ++r)
                    val[r] = acc[r] * (c == 0 ? gc[r] : gc2[r]);
#pragma unroll
                for (int e = 0; e < 6; ++e)
                    st[c][e] = pack_pk(val[2 * e], val[2 * e + 1]);
            } else {
                float s = 0.f;
#pragma unroll
                for (int r = 0; r < 12; ++r)
                    s += acc[r] * (c == 0 ? gc[r] : gc2[r]);
                if (c == 0) sm = s;
                else        sv += coef[c] * s;
            }
        }
    }

    // ---- epilogue: combine halves, atomically accumulate over p ----
    sm += __shfl_xor(sm, 32, 64);
    sv += __shfl_xor(sv, 32, 64);
    if (lane < 32) {
        atomicAdd(&out[2 * (n0 + nl)], sm);
        atomicAdd(&out[2 * (n0 + nl) + 1], sv);
    }
}

extern "C" void kernel_launch(void* const* d_in, const int* in_sizes, int n_in,
                              void* d_out, int out_size, void* d_ws, size_t ws_size,
                              hipStream_t stream) {
    const float* X      = (const float*)d_in[0];
    const int*   perm   = (const int*)d_in[1];
    const float* meanw0 = (const float*)d_in[2];
    const float* meanw  = (const float*)d_in[3];
    const float* varw0  = (const float*)d_in[4];
    const float* varw   = (const float*)d_in[5];
    float* out = (float*)d_out;

    // workspace: [W0: 2800 f32][WA: 1,003,520 f16]
    float*     W0 = (float*)d_ws;
    _Float16*  WA = (_Float16*)((char*)d_ws + 11200);

    // zero output for atomic accumulation (stream-ordered, graph-safe)
    hipMemsetAsync(d_out, 0, (size_t)out_size * sizeof(float), stream);

    int prep_n = NCHAIN * PP * OO + NCHAIN * (DD - 1) * PP * 32 * 32;
    hipLaunchKernelGGL(prep_kernel, dim3((prep_n + 255) / 256), dim3(256), 0,
                       stream, meanw0, meanw, varw0, varw, W0, WA);

    dim3 grid(NPTS / 128, PP);   // 4 waves/block, 32 pts/wave, all 7 chains/wave
    hipLaunchKernelGGL(chain_kernel, grid, dim3(256), 0, stream,
                       X, perm, W0, WA, out);
}

// Round 7
// 192.039 us; speedup vs baseline: 1.1661x; 1.1661x over previous
//
#include <hip/hip_runtime.h>
#include <math.h>

#define NPTS 32768
#define DD 8
#define OO 20      // ORDER+1
#define PP 20
#define NCHAIN 7   // c=0: mean chain; c=1..6: variance moment k=c
#define NT 2       // point-tiles (32 pts each) per wave — amortizes A loads

typedef _Float16 half8 __attribute__((ext_vector_type(8)));
typedef __fp16 fp16x2 __attribute__((ext_vector_type(2)));
typedef float floatx16 __attribute__((ext_vector_type(16)));

// sigma: row permutation baked into A so that C-layout output == next B layout
// (swap rows 4..7 <-> 8..11; identity elsewhere)
__device__ __forceinline__ int sigma_row(int m) {
    return (m >= 4 && m < 12) ? (m ^ 12) : m;
}

// ---------------------------------------------------------------------------
// Prep:
//   W0[c][p][q]  fp32 = c==0 ? exp(meanw0) : exp(2*meanw0 + c*varw0)
//   WA[c][i][p][m][k] f16 (32x32, zero-padded) = W[sigma(m)][k] where
//       W[q'][o] = c==0 ? exp(meanw[i][p][o][q']) : exp(2*m + c*v)
// binom stays in the fp32 gate (up to 92378 > f16 max; basis in [0,1]).
// ---------------------------------------------------------------------------
__global__ void prep_kernel(const float* __restrict__ meanw0,
                            const float* __restrict__ meanw,
                            const float* __restrict__ varw0,
                            const float* __restrict__ varw,
                            float* __restrict__ W0,
                            _Float16* __restrict__ WA) {
    int e = blockIdx.x * 256 + threadIdx.x;
    const int n0 = NCHAIN * PP * OO;                 // 2800
    const int nW = NCHAIN * (DD - 1) * PP * 32 * 32; // 1,003,520
    if (e < n0) {
        int q = e % OO;
        int rem = e / OO;
        int p = rem % PP;
        int c = rem / PP;
        float m = meanw0[p * OO + q];
        W0[e] = (c == 0) ? __expf(m) : __expf(2.f * m + (float)c * varw0[p * OO + q]);
    } else if (e < n0 + nW) {
        int idx = e - n0;
        int k = idx & 31; idx >>= 5;
        int m = idx & 31; idx >>= 5;
        int p = idx % PP; idx /= PP;
        int i = idx % (DD - 1);
        int c = idx / (DD - 1);
        int q = sigma_row(m);
        float v = 0.f;
        if (q < OO && k < OO) {
            int mi = ((i * PP + p) * OO + k) * OO + q;   // meanw[i][p][o=k][q']
            float mm = meanw[mi];
            v = (c == 0) ? __expf(mm) : __expf(2.f * mm + (float)c * varw[mi]);
        }
        WA[e - n0] = (_Float16)v;
    }
}

// basis b_q = binom[q] t^q (1-t)^(19-q), fp32
__device__ __forceinline__ void basis20(float tv, float* g) {
    constexpr float binom[OO] = {
        1.f, 19.f, 171.f, 969.f, 3876.f, 11628.f, 27132.f, 50388.f, 75582.f,
        92378.f, 92378.f, 75582.f, 50388.f, 27132.f, 11628.f, 3876.f, 969.f,
        171.f, 19.f, 1.f};
    float a = tv, b = 1.f - tv, v = 1.f;
#pragma unroll
    for (int q = 0; q < OO; ++q) { g[q] = v; v *= a; }
    v = 1.f;
#pragma unroll
    for (int q = OO - 1; q >= 0; --q) { g[q] = g[q] * v * binom[q]; v *= b; }
}

__device__ __forceinline__ unsigned pack_pk(float x, float y) {
    union { fp16x2 h; unsigned u; } cv;
    cv.h = __builtin_amdgcn_cvt_pkrtz(x, y);
    return cv.u;
}

// ---------------------------------------------------------------------------
// One wave = one p x NT*32 points x all 7 chains. State st[tile][c][0..5] is
// the f16 B-layout activation. Sigma row-permutation of A makes the MFMA C
// output pack DIRECTLY into the same lane's next-step B dwords:
//   B0.u[e] = st[e];  B1 = {st[4], st[5], 0, 0}
// Gate in C-space: reg r multiplies g[r+8*hi] (r<8), g[r+8]/0 (r>=8).
// A0/A1 loaded once per (c,i), applied to NT tiles. No DS ops in the loop.
// ---------------------------------------------------------------------------
__global__ __launch_bounds__(256, 2) void chain_kernel(
    const float* __restrict__ X, const int* __restrict__ perm,
    const float* __restrict__ W0, const _Float16* __restrict__ WA,
    float* __restrict__ partial) {
    const int lane = threadIdx.x & 63;
    const int wv = threadIdx.x >> 6;
    const int nl = lane & 31;
    const bool hi = (lane >> 5) != 0;
    const int n0 = (blockIdx.x * 4 + wv) * (32 * NT);
    const int p = blockIdx.y;

    // permuted X entries (perm is wave-uniform)
    float t[NT][DD];
#pragma unroll
    for (int tile = 0; tile < NT; ++tile)
#pragma unroll
        for (int i = 0; i < DD; ++i)
            t[tile][i] = X[(size_t)(n0 + tile * 32 + nl) * DD + perm[p * DD + i]];

    unsigned st[NT][NCHAIN][6];

    // ---- init directly in B layout: f0[k] = W0[c][p][k] * gate0[k] ----
#pragma unroll
    for (int tile = 0; tile < NT; ++tile) {
        float g[OO];
        basis20(t[tile][0], g);
        float gc[12], gc2[12];
#pragma unroll
        for (int r = 0; r < 8; ++r) gc[r] = hi ? g[r + 8] : g[r];
#pragma unroll
        for (int r = 8; r < 12; ++r) gc[r] = hi ? 0.f : g[r + 8];
#pragma unroll
        for (int r = 0; r < 12; ++r) gc2[r] = gc[r] * gc[r];
#pragma unroll
        for (int c = 0; c < NCHAIN; ++c) {
            const float* w0r = W0 + (c * PP + p) * OO;
            float val[12];
#pragma unroll
            for (int r = 0; r < 8; ++r) {
                float ws = hi ? w0r[r + 8] : w0r[r];
                val[r] = ws * (c == 0 ? gc[r] : gc2[r]);
            }
#pragma unroll
            for (int r = 8; r < 12; ++r) {
                float ws = hi ? 0.f : w0r[r + 8];
                val[r] = ws * (c == 0 ? gc[r] : gc2[r]);
            }
#pragma unroll
            for (int e = 0; e < 6; ++e)
                st[tile][c][e] = pack_pk(val[2 * e], val[2 * e + 1]);
        }
    }

    // per-lane A-operand offset (A row m = nl, k = hi*8 + j; +16 for MFMA1)
    const int aoff = nl * 32 + (hi ? 8 : 0);
    const float coef[NCHAIN] = {0.f, 1.f, 0.5f, 1.f / 6.f, 1.f / 24.f,
                                1.f / 120.f, 1.f / 720.f};
    float sm[NT], sv[NT];
#pragma unroll
    for (int tile = 0; tile < NT; ++tile) { sm[tile] = 0.f; sv[tile] = 0.f; }

#pragma unroll
    for (int i = 1; i < DD; ++i) {
        float gc[NT][12], gc2[NT][12];
#pragma unroll
        for (int tile = 0; tile < NT; ++tile) {
            float g[OO];
            basis20(t[tile][i], g);
#pragma unroll
            for (int r = 0; r < 8; ++r) gc[tile][r] = hi ? g[r + 8] : g[r];
#pragma unroll
            for (int r = 8; r < 12; ++r) gc[tile][r] = hi ? 0.f : g[r + 8];
#pragma unroll
            for (int r = 0; r < 12; ++r) gc2[tile][r] = gc[tile][r] * gc[tile][r];
        }

#pragma unroll
        for (int c = 0; c < NCHAIN; ++c) {
            // one A load per (c,i), shared across NT tiles
            const _Float16* wa =
                WA + (size_t)(((c * (DD - 1)) + (i - 1)) * PP + p) * 1024 + aoff;
            half8 A0 = *(const half8*)(wa);
            half8 A1 = *(const half8*)(wa + 16);

#pragma unroll
            for (int tile = 0; tile < NT; ++tile) {
                union { unsigned u[4]; half8 h; } B0, B1;
                B0.u[0] = st[tile][c][0]; B0.u[1] = st[tile][c][1];
                B0.u[2] = st[tile][c][2]; B0.u[3] = st[tile][c][3];
                B1.u[0] = st[tile][c][4]; B1.u[1] = st[tile][c][5];
                B1.u[2] = 0u;             B1.u[3] = 0u;

                floatx16 acc = {};
                acc = __builtin_amdgcn_mfma_f32_32x32x16_f16(A0, B0.h, acc, 0, 0, 0);
                acc = __builtin_amdgcn_mfma_f32_32x32x16_f16(A1, B1.h, acc, 0, 0, 0);

                if (i < DD - 1) {
                    float val[12];
#pragma unroll
                    for (int r = 0; r < 12; ++r)
                        val[r] = acc[r] * (c == 0 ? gc[tile][r] : gc2[tile][r]);
#pragma unroll
                    for (int e = 0; e < 6; ++e)
                        st[tile][c][e] = pack_pk(val[2 * e], val[2 * e + 1]);
                } else {
                    float s = 0.f;
#pragma unroll
                    for (int r = 0; r < 12; ++r)
                        s += acc[r] * (c == 0 ? gc[tile][r] : gc2[tile][r]);
                    if (c == 0) sm[tile] = s;
                    else        sv[tile] += coef[c] * s;
                }
            }
        }
    }

    // ---- epilogue: combine half-waves, write per-p partials ----
#pragma unroll
    for (int tile = 0; tile < NT; ++tile) {
        float m = sm[tile] + __shfl_xor(sm[tile], 32, 64);
        float v = sv[tile] + __shfl_xor(sv[tile], 32, 64);
        if (lane < 32) {
            partial[(size_t)p * NPTS + n0 + tile * 32 + nl] = m;
            partial[(size_t)(PP + p) * NPTS + n0 + tile * 32 + nl] = v;
        }
    }
}

// ---------------------------------------------------------------------------
// Reduce over p: out[n][0] = sum_p mean_p[n]; out[n][1] = sum_p var_p[n]
// ---------------------------------------------------------------------------
__global__ void reduce_kernel(const float* __restrict__ partial,
                              float* __restrict__ out) {
    int n = blockIdx.x * 256 + threadIdx.x;
    float m = 0.f, v = 0.f;
#pragma unroll
    for (int p = 0; p < PP; ++p) {
        m += partial[(size_t)p * NPTS + n];
        v += partial[(size_t)(PP + p) * NPTS + n];
    }
    out[2 * n] = m;
    out[2 * n + 1] = v;
}

extern "C" void kernel_launch(void* const* d_in, const int* in_sizes, int n_in,
                              void* d_out, int out_size, void* d_ws, size_t ws_size,
                              hipStream_t stream) {
    const float* X      = (const float*)d_in[0];
    const int*   perm   = (const int*)d_in[1];
    const float* meanw0 = (const float*)d_in[2];
    const float* meanw  = (const float*)d_in[3];
    const float* varw0  = (const float*)d_in[4];
    const float* varw   = (const float*)d_in[5];
    float* out = (float*)d_out;

    // workspace: [W0: 2800 f32][WA: 1,003,520 f16][partial: 2*20*32768 f32]
    float*     W0      = (float*)d_ws;
    _Float16*  WA      = (_Float16*)((char*)d_ws + 11200);
    float*     partial = (float*)((char*)d_ws + 11200 + 2007040);

    int prep_n = NCHAIN * PP * OO + NCHAIN * (DD - 1) * PP * 32 * 32;
    hipLaunchKernelGGL(prep_kernel, dim3((prep_n + 255) / 256), dim3(256), 0,
                       stream, meanw0, meanw, varw0, varw, W0, WA);

    dim3 grid(NPTS / (128 * NT), PP);  // 4 waves/block, NT*32 pts/wave
    hipLaunchKernelGGL(chain_kernel, grid, dim3(256), 0, stream,
                       X, perm, W0, WA, partial);

    hipLaunchKernelGGL(reduce_kernel, dim3(NPTS / 256), dim3(256), 0, stream,
                       partial, out);
}